// Round 3
// baseline (818.814 us; speedup 1.0000x reference)
//
#include <hip/hip_runtime.h>
#include <hip/hip_bf16.h>
#include <math.h>

#define NBAG 512
#define NPB 64
#define DIM 1024
#define NCLS 53
#define NSTEP 63
#define MAXROWS 16384  // level-1 worst case: 512 bags * 32 merges
#define LMAX 8         // levels 1..LMAX via batched GEMM; deeper via k_deep
                       // (measured: LMAX=4 -> k_deep 1391us; LMAX=14 -> +12 launches, +95us;
                       //  8-phase k_fc8 port for l<=2 -> +72us, reverted)

typedef __attribute__((ext_vector_type(8))) short short8;
typedef __attribute__((ext_vector_type(4))) short short4v;
typedef __attribute__((ext_vector_type(4))) float f32x4;

__device__ __forceinline__ short bf16bits(float x) {
  __hip_bfloat16 h = __float2bfloat16(x);
  return *reinterpret_cast<short*>(&h);
}

// fast tanh: 1 - 2/(e^{2x}+1). Feature path only — never in the node-weight
// computation (tree order must not change).
__device__ __forceinline__ float fast_tanh(float x) {
  float e = __expf(2.0f * x);
  return 1.0f - __fdividef(2.0f, e + 1.0f);
}

// global -> LDS direct copy, 16B per lane, dest = wave-uniform base + lane*16
__device__ __forceinline__ void gld16(const void* g, void* l) {
  __builtin_amdgcn_global_load_lds(
      (const __attribute__((address_space(1))) void*)g,
      (__attribute__((address_space(3))) void*)(unsigned)(uintptr_t)l,
      16, 0, 0);
}

// ---------------------------------------------------------------------------
// K1: per-bag node weights + bf16 tanh leaves + fused weight f32->bf16 tail.
// R14: fence-free rewrite. R12/R13's LDS-transpose staging required asm
// memory fences (SIMT alias analysis would otherwise reorder the strided
// ds_reads above other lanes' ds_writes), and those fences blocked all
// cross-row load pipelining -> latency-bound at 2.6 TB/s regardless of LDS
// size. Instead: original strided scalar loads (coalesced, 256 B/wave-instr,
// 16 independent loads/row, no LDS round-trip), tanh computed from the same
// registers, and 256-thread blocks so 8 blocks/CU hide latency.
// nw arithmetic bitwise-identical to the proven R5 ordering.
// ---------------------------------------------------------------------------
__global__ __launch_bounds__(256) void k_prep(const float* __restrict__ rep,
                                              float* __restrict__ nw,
                                              __hip_bfloat16* __restrict__ tfeats,
                                              const float* __restrict__ w1,
                                              __hip_bfloat16* __restrict__ w1b,
                                              const float* __restrict__ w2,
                                              __hip_bfloat16* __restrict__ w2b) {
  int b = blockIdx.x;
  const float* bag = rep + (size_t)b * NPB * DIM;
  __shared__ float inv_n[NPB];
  __shared__ float dist[NPB];
  __shared__ alignas(16) float S[DIM];
  int t = threadIdx.x, wave = t >> 6, lane = t & 63;

  // ---- pass 1: strided scalar loads -> exact-order norm + tanh from regs
  for (int n = wave; n < NPB; n += 4) {
    const float* x = bag + (size_t)n * DIM;
    float f[16];
    #pragma unroll
    for (int k = 0; k < 16; k++) f[k] = x[lane + 64 * k];
    float acc = 0.f;
    #pragma unroll
    for (int k = 0; k < 16; k++) acc += f[k] * f[k];
    __hip_bfloat16* tr = tfeats + ((((size_t)b << 6) + n) << 10);
    #pragma unroll
    for (int k = 0; k < 16; k++) {
      short o = bf16bits(fast_tanh(f[k]));
      tr[lane + 64 * k] = *reinterpret_cast<__hip_bfloat16*>(&o);
    }
    for (int off = 32; off; off >>= 1) acc += __shfl_xor(acc, off);
    if (lane == 0) inv_n[n] = 1.0f / sqrtf(acc);
  }
  __syncthreads();

  // ---- pass 2: S, vectorized across columns; per-column n-order unchanged
  {
    const f32x4* br = (const f32x4*)bag;
    f32x4 acc = (f32x4){0.f, 0.f, 0.f, 0.f};
    #pragma unroll 16
    for (int n = 0; n < NPB; n++) {
      f32x4 v = br[n * 256 + t];
      float w = inv_n[n];
      acc.x += v.x * w; acc.y += v.y * w;
      acc.z += v.z * w; acc.w += v.w * w;
    }
    ((f32x4*)S)[t] = acc;
  }
  __syncthreads();

  // ---- pass 3: dist, strided scalar loads, exact-order dot with S
  for (int n = wave; n < NPB; n += 4) {
    const float* x = bag + (size_t)n * DIM;
    float f[16];
    #pragma unroll
    for (int k = 0; k < 16; k++) f[k] = x[lane + 64 * k];
    float acc = 0.f;
    #pragma unroll
    for (int k = 0; k < 16; k++) acc += f[k] * S[lane + 64 * k];
    for (int off = 32; off; off >>= 1) acc += __shfl_xor(acc, off);
    if (lane == 0) dist[n] = acc * inv_n[n];
  }
  __syncthreads();

  if (t < 64) {
    float v = dist[t], m = v;
    for (int off = 32; off; off >>= 1) m = fmaxf(m, __shfl_xor(m, off));
    float e = expf(v - m), s = e;
    for (int off = 32; off; off >>= 1) s += __shfl_xor(s, off);
    nw[b * NPB + t] = e / s;
  }

  // ---- fused weight conversion tail (vectorized, grid-strided; elementwise
  // so the remapped 256-thread grid-stride is bitwise-identical)
  {
    const int nv1 = (DIM * 2 * DIM) / 4;
    const int nv2 = (DIM * DIM) / 4;
    for (int i = b * 256 + t; i < nv1 + nv2; i += NBAG * 256) {
      if (i < nv1) {
        f32x4 v = ((const f32x4*)w1)[i];
        short4v o;
        o.x = bf16bits(v.x); o.y = bf16bits(v.y);
        o.z = bf16bits(v.z); o.w = bf16bits(v.w);
        ((short4v*)w1b)[i] = o;
      } else {
        f32x4 v = ((const f32x4*)w2)[i - nv1];
        short4v o;
        o.x = bf16bits(v.x); o.y = bf16bits(v.y);
        o.z = bf16bits(v.z); o.w = bf16bits(v.w);
        ((short4v*)w2b)[i - nv1] = o;
      }
    }
  }
}

// ---------------------------------------------------------------------------
// K2: per-bag Huffman merge order + level. 4 bags per block.
// ---------------------------------------------------------------------------
__global__ __launch_bounds__(256) void k_merge_levels(const float* __restrict__ nw,
                                                      unsigned* __restrict__ lvlbuf,
                                                      unsigned* __restrict__ cnt) {
  int b = blockIdx.x * 4 + (threadIdx.x >> 6);
  int lane = threadIdx.x & 63;
  const float INF = __int_as_float(0x7f800000);
  float w = nw[b * NPB + lane];
  bool alive = true;
  int ready = 0;
  int mycnt = 0;

  for (int t = 0; t < NSTEP; t++) {
    float v = alive ? w : INF; int i = lane;
    for (int off = 32; off; off >>= 1) {
      float v2 = __shfl_xor(v, off); int j2 = __shfl_xor(i, off);
      if (v2 < v || (v2 == v && j2 < i)) { v = v2; i = j2; }
    }
    int i1 = i;
    float vv = (alive && lane != i1) ? w : INF; int ii = lane;
    for (int off = 32; off; off >>= 1) {
      float v2 = __shfl_xor(vv, off); int j2 = __shfl_xor(ii, off);
      if (v2 < vv || (v2 == vv && j2 < ii)) { vv = v2; ii = j2; }
    }
    int i2 = ii;
    float w1v = __shfl(w, i1), w2v = __shfl(w, i2);
    if (lane == i1) w = w1v + w2v;
    if (lane == i2) alive = false;
    int r1 = __shfl(ready, i1), r2 = __shfl(ready, i2);
    int lvl = max(r1, r2) + 1;
    int rank = __shfl(mycnt, lvl - 1);
    if (lane == lvl - 1) mycnt++;
    if (lane == i1) ready = lvl;
    if (lane == 0)
      lvlbuf[b * NSTEP + t] = (unsigned)i1 | ((unsigned)i2 << 6) |
                              ((unsigned)lvl << 12) | ((unsigned)rank << 18);
  }
  cnt[b * 64 + lane] = (unsigned)mycnt;
}

// K3: per-level exclusive scan over bags
__global__ __launch_bounds__(512) void k_bagscan(const unsigned* __restrict__ cnt,
                                                 unsigned* __restrict__ bagoff,
                                                 unsigned* __restrict__ levtot) {
  int l = blockIdx.x + 1;
  int b = threadIdx.x;
  __shared__ unsigned s[512];
  unsigned v = cnt[b * 64 + (l - 1)];
  s[b] = v; __syncthreads();
  for (int o = 1; o < 512; o <<= 1) {
    unsigned x = (b >= o) ? s[b - o] : 0u; __syncthreads();
    s[b] += x; __syncthreads();
  }
  bagoff[l * 512 + b] = s[b] - v;
  if (b == 511) levtot[l] = s[511];
}

// K5: scatter merges into level-sorted worklist (fused level-offset scan).
__global__ __launch_bounds__(256) void k_scatter(const unsigned* __restrict__ lvlbuf,
                                                 const unsigned* __restrict__ levtot,
                                                 const unsigned* __restrict__ bagoff,
                                                 unsigned* __restrict__ wl,
                                                 unsigned* __restrict__ off_out) {
  __shared__ unsigned off_s[65];
  int t = threadIdx.x;
  if (t < 64) {
    unsigned v = (t >= 1) ? levtot[t] : 0u;
    unsigned x = v;
    for (int o = 1; o < 64; o <<= 1) {
      unsigned y = __shfl_up(x, o);
      if (t >= o) x += y;
    }
    off_s[t] = x - v;
    if (t == 63) off_s[64] = x;
    if (blockIdx.x == 0) {
      off_out[t] = x - v;
      if (t == 63) off_out[64] = x;
    }
  }
  __syncthreads();

  int idx = blockIdx.x * 256 + t;
  int b = idx / NSTEP, st = idx % NSTEP;
  unsigned e = lvlbuf[idx];
  unsigned i1 = e & 63, i2 = (e >> 6) & 63, lvl = (e >> 12) & 63, rank = (e >> 18) & 31;
  unsigned pos = off_s[lvl] + bagoff[lvl * 512 + b] + rank;
  wl[pos] = (unsigned)b | (i1 << 9) | (i2 << 15) | ((st == NSTEP - 1 ? 1u : 0u) << 21);
}

// ---------------------------------------------------------------------------
// K7: batched MFMA GEMM for one level. BM=256 x BN=128, BK=64, 8 waves,
// wave-tile 64x64 (4M x 2N). Proven R11 body (bit-exact outputs).
// ---------------------------------------------------------------------------
template <int KTOT, bool FC1>
__global__ __launch_bounds__(512) void k_fc(const __hip_bfloat16* __restrict__ Asrc,
                                            const __hip_bfloat16* __restrict__ wB,
                                            const float* __restrict__ bias,
                                            const unsigned* __restrict__ wl,
                                            const unsigned* __restrict__ off,
                                            __hip_bfloat16* __restrict__ hbuf,
                                            __hip_bfloat16* __restrict__ tfeats,
                                            float* __restrict__ rootfeat,
                                            int level) {
  __shared__ alignas(16) short As[256 * 64];   // 32 KB
  __shared__ alignas(16) short Bs[128 * 64];   // 16 KB
  __shared__ unsigned wle[256];

  int nwg = (int)gridDim.x;
  int hw = (int)blockIdx.x;
  int q = nwg >> 3, r = nwg & 7;
  int xcd = hw & 7, ii = hw >> 3;
  int wid = (xcd < r ? xcd * (q + 1) : r * (q + 1) + (xcd - r) * q) + ii;
  int nbase = (wid & 7) * 128;     // 8 N-panels of 128
  int mbase = (wid >> 3) * 256;    // M-tiles of 256

  int c0 = (int)off[level];
  int count = (int)off[level + 1] - c0;
  if (mbase >= count) return;
  int t = threadIdx.x, wv = t >> 6, lane = t & 63;
  if (t < 256) wle[t] = wl[c0 + min(mbase + t, count - 1)];
  __syncthreads();

  int lr = lane >> 3, p = lane & 7;
  const __hip_bfloat16* aptrA[4];
  const __hip_bfloat16* aptrB[4];
  const __hip_bfloat16* bptr[2];
  #pragma unroll
  for (int c = 0; c < 4; c++) {
    int rc = (wv * 4 + c) * 8 + lr;    // 0..255: A-row this lane stages
    int u = p ^ (rc & 7);
    if (FC1) {
      unsigned e = wle[rc];
      int bidx = e & 511, s1 = (e >> 9) & 63, s2 = (e >> 15) & 63;
      aptrA[c] = Asrc + (((size_t)(bidx << 6) + s1) << 10) + (u << 3);
      aptrB[c] = Asrc + (((size_t)(bidx << 6) + s2) << 10) + (u << 3);
    } else {
      aptrA[c] = Asrc + ((size_t)(mbase + rc) << 10) + (u << 3);
      aptrB[c] = aptrA[c];
    }
  }
  #pragma unroll
  for (int c = 0; c < 2; c++) {
    int rc = (wv * 2 + c) * 8 + lr;    // 0..127: B-row this lane stages
    int u = p ^ (rc & 7);
    bptr[c] = wB + (size_t)(nbase + rc) * KTOT + (u << 3);
  }

  f32x4 acc[4][4];
  #pragma unroll
  for (int i = 0; i < 4; i++)
    #pragma unroll
    for (int j = 0; j < 4; j++) acc[i][j] = (f32x4){0.f, 0.f, 0.f, 0.f};

  int mh = wv >> 1, nh = wv & 1;       // 4M x 2N wave grid

  for (int k0 = 0; k0 < KTOT; k0 += 64) {
    #pragma unroll
    for (int c = 0; c < 4; c++) {
      int ch = wv * 4 + c;             // 0..31 A-chunks (8 rows each)
      const __hip_bfloat16* g =
          (FC1 && k0 >= DIM) ? (aptrB[c] + (k0 - DIM)) : (aptrA[c] + k0);
      gld16(g, &As[ch << 9]);
    }
    #pragma unroll
    for (int c = 0; c < 2; c++) {
      int ch = wv * 2 + c;             // 0..15 B-chunks
      gld16(bptr[c] + k0, &Bs[ch << 9]);
    }
    __syncthreads();
    #pragma unroll
    for (int kc = 0; kc < 2; kc++) {
      short8 a[4], bb[4];
      #pragma unroll
      for (int mi = 0; mi < 4; mi++) {
        int rr = mh * 64 + mi * 16 + (lane & 15);
        int u = (kc * 4 + (lane >> 4)) ^ (rr & 7);
        a[mi] = *(const short8*)&As[rr * 64 + u * 8];
      }
      #pragma unroll
      for (int ni = 0; ni < 4; ni++) {
        int rr = nh * 64 + ni * 16 + (lane & 15);
        int u = (kc * 4 + (lane >> 4)) ^ (rr & 7);
        bb[ni] = *(const short8*)&Bs[rr * 64 + u * 8];
      }
      #pragma unroll
      for (int mi = 0; mi < 4; mi++)
        #pragma unroll
        for (int ni = 0; ni < 4; ni++)
          acc[mi][ni] = __builtin_amdgcn_mfma_f32_16x16x32_bf16(a[mi], bb[ni],
                                                                acc[mi][ni], 0, 0, 0);
    }
    __syncthreads();
  }

  #pragma unroll
  for (int mi = 0; mi < 4; mi++) {
    #pragma unroll
    for (int reg = 0; reg < 4; reg++) {
      int m_loc = mh * 64 + mi * 16 + ((lane >> 4) << 2) + reg;
      int m = mbase + m_loc;
      if (m >= count) continue;
      #pragma unroll
      for (int ni = 0; ni < 4; ni++) {
        int n = nbase + nh * 64 + ni * 16 + (lane & 15);
        float v = acc[mi][ni][reg] + bias[n];
        if (FC1) {
          hbuf[(size_t)m * DIM + n] = __float2bfloat16(fast_tanh(v));
        } else {
          unsigned e = wle[m_loc];
          int bidx = e & 511, d = (e >> 9) & 63;
          tfeats[(((size_t)(bidx << 6) + d) << 10) + n] = __float2bfloat16(fast_tanh(v));
          if (e >> 21) rootfeat[(size_t)bidx * DIM + n] = v;
        }
      }
    }
  }
}

// ---------------------------------------------------------------------------
// K7b: deep-level fallback (> LMAX) + fused final scores. One block per bag.
// ---------------------------------------------------------------------------
#define XP(i) ((i) + ((i) >> 3))
__global__ __launch_bounds__(1024) void k_deep(__hip_bfloat16* __restrict__ tfeats,
                                               const __hip_bfloat16* __restrict__ w1b,
                                               const float* __restrict__ b1,
                                               const __hip_bfloat16* __restrict__ w2b,
                                               const float* __restrict__ b2,
                                               const unsigned* __restrict__ lvlbuf,
                                               float* __restrict__ rootfeat,
                                               const float* __restrict__ rel,
                                               float* __restrict__ out) {
  int b = blockIdx.x;
  __shared__ float xs[XP(2048) + 1];
  __shared__ float hs[XP(1024) + 1];
  __shared__ unsigned steps[NSTEP];
  int t = threadIdx.x, wv = t >> 6, lane = t & 63;
  if (t < NSTEP) steps[t] = lvlbuf[b * NSTEP + t];
  __syncthreads();

  for (int s = 0; s < NSTEP; s++) {
    unsigned e = steps[s];
    int lvl = (int)((e >> 12) & 63);
    if (lvl <= LMAX) continue;
    int i1 = (int)(e & 63), i2 = (int)((e >> 6) & 63);
    const __hip_bfloat16* r1 = tfeats + ((((size_t)b << 6) + i1) << 10);
    const __hip_bfloat16* r2 = tfeats + ((((size_t)b << 6) + i2) << 10);
    xs[XP(t)] = __bfloat162float(r1[t]);
    xs[XP(1024 + t)] = __bfloat162float(r2[t]);
    __syncthreads();
    for (int r = 0; r < 64; r++) {
      int n = r * 16 + wv;
      const short8* wr = (const short8*)(w1b + (size_t)n * 2048);
      float acc = 0.f;
      for (int c = lane; c < 256; c += 64) {
        short8 w8 = wr[c];
        #pragma unroll
        for (int j = 0; j < 8; j++) {
          float wf = __uint_as_float(((unsigned)(unsigned short)w8[j]) << 16);
          acc += xs[XP(c * 8 + j)] * wf;
        }
      }
      for (int off = 32; off; off >>= 1) acc += __shfl_xor(acc, off);
      if (lane == 0) hs[XP(n)] = fast_tanh(acc + b1[n]);
    }
    __syncthreads();
    for (int r = 0; r < 64; r++) {
      int n = r * 16 + wv;
      const short8* wr = (const short8*)(w2b + (size_t)n * 1024);
      float acc = 0.f;
      for (int c = lane; c < 128; c += 64) {
        short8 w8 = wr[c];
        #pragma unroll
        for (int j = 0; j < 8; j++) {
          float wf = __uint_as_float(((unsigned)(unsigned short)w8[j]) << 16);
          acc += hs[XP(c * 8 + j)] * wf;
        }
      }
      for (int off = 32; off; off >>= 1) acc += __shfl_xor(acc, off);
      if (lane == 0) {
        float f = acc + b2[n];
        tfeats[((((size_t)b << 6) + i1) << 10) + n] = __float2bfloat16(fast_tanh(f));
        if (s == NSTEP - 1) rootfeat[(size_t)b * DIM + n] = f;
      }
    }
    __syncthreads();
  }

  // ---- fused scores: sigmoid(rootfeat[b] @ rel^T)
  __shared__ float fr[DIM];
  fr[t] = rootfeat[(size_t)b * DIM + t];
  __syncthreads();
  for (int c = wv; c < NCLS; c += 16) {
    const float* w = rel + (size_t)c * DIM;
    float acc = 0.f;
    for (int j = lane; j < DIM; j += 64) acc += fr[j] * w[j];
    for (int off = 32; off; off >>= 1) acc += __shfl_xor(acc, off);
    if (lane == 0) out[b * NCLS + c] = 1.0f / (1.0f + expf(-acc));
  }
}

// ---------------------------------------------------------------------------
extern "C" void kernel_launch(void* const* d_in, const int* in_sizes, int n_in,
                              void* d_out, int out_size, void* d_ws, size_t ws_size,
                              hipStream_t stream) {
  const float* rep = (const float*)d_in[0];
  const float* w1  = (const float*)d_in[1];
  const float* b1  = (const float*)d_in[2];
  const float* w2  = (const float*)d_in[3];
  const float* b2  = (const float*)d_in[4];
  const float* rel = (const float*)d_in[5];
  float* out = (float*)d_out;

  char* ws = (char*)d_ws;
  __hip_bfloat16* tfeats = (__hip_bfloat16*)ws; ws += (size_t)NBAG * NPB * DIM * 2;
  __hip_bfloat16* hbuf   = (__hip_bfloat16*)ws; ws += (size_t)MAXROWS * DIM * 2;
  __hip_bfloat16* w1b    = (__hip_bfloat16*)ws; ws += (size_t)DIM * 2 * DIM * 2;
  __hip_bfloat16* w2b    = (__hip_bfloat16*)ws; ws += (size_t)DIM * DIM * 2;
  float* rootfeat        = (float*)ws;          ws += (size_t)NBAG * DIM * 4;
  float* nw              = (float*)ws;          ws += (size_t)NBAG * NPB * 4;
  unsigned* lvlbuf       = (unsigned*)ws;       ws += (size_t)NBAG * NSTEP * 4;
  unsigned* cnt          = (unsigned*)ws;       ws += (size_t)NBAG * 64 * 4;
  unsigned* bagoff       = (unsigned*)ws;       ws += (size_t)64 * 512 * 4;
  unsigned* levtot       = (unsigned*)ws;       ws += 64 * 4;
  unsigned* off          = (unsigned*)ws;       ws += 128 * 4;
  unsigned* wl           = (unsigned*)ws;       ws += (size_t)NBAG * NSTEP * 4;

  k_prep<<<NBAG, 256, 0, stream>>>(rep, nw, tfeats, w1, w1b, w2, w2b);
  k_merge_levels<<<NBAG / 4, 256, 0, stream>>>(nw, lvlbuf, cnt);
  k_bagscan<<<63, 512, 0, stream>>>(cnt, bagoff, levtot);
  k_scatter<<<126, 256, 0, stream>>>(lvlbuf, levtot, bagoff, wl, off);

  for (int l = 1; l <= LMAX; l++) {
    int cap = 64 / (l + 1); if (cap > 32) cap = 32;
    int capM = 2 * cap;                       // 256-row M-tiles capacity
    k_fc<2 * DIM, true><<<dim3(8 * capM), 512, 0, stream>>>(
        tfeats, w1b, b1, wl, off, hbuf, nullptr, nullptr, l);
    k_fc<DIM, false><<<dim3(8 * capM), 512, 0, stream>>>(
        hbuf, w2b, b2, wl, off, nullptr, tfeats, rootfeat, l);
  }
  k_deep<<<NBAG, 1024, 0, stream>>>(tfeats, w1b, b1, w2b, b2, lvlbuf, rootfeat,
                                    rel, out);
}

// Round 4
// 817.513 us; speedup vs baseline: 1.0016x; 1.0016x over previous
//
#include <hip/hip_runtime.h>
#include <hip/hip_bf16.h>
#include <math.h>

#define NBAG 512
#define NPB 64
#define DIM 1024
#define NCLS 53
#define NSTEP 63
#define MAXROWS 16384  // level-1 worst case: 512 bags * 32 merges
#define LMAX 8         // levels 1..LMAX via batched GEMM; deeper via k_deep
                       // (measured: LMAX=4 -> k_deep 1391us; LMAX=14 -> +12 launches, +95us;
                       //  8-phase k_fc8 port for l<=2 -> +72us, reverted)

typedef __attribute__((ext_vector_type(8))) short short8;
typedef __attribute__((ext_vector_type(4))) short short4v;
typedef __attribute__((ext_vector_type(4))) float f32x4;

__device__ __forceinline__ short bf16bits(float x) {
  __hip_bfloat16 h = __float2bfloat16(x);
  return *reinterpret_cast<short*>(&h);
}

// fast tanh: 1 - 2/(e^{2x}+1). Feature path only — never in the node-weight
// computation (tree order must not change).
__device__ __forceinline__ float fast_tanh(float x) {
  float e = __expf(2.0f * x);
  return 1.0f - __fdividef(2.0f, e + 1.0f);
}

// global -> LDS direct copy, 16B per lane, dest = wave-uniform base + lane*16
__device__ __forceinline__ void gld16(const void* g, void* l) {
  __builtin_amdgcn_global_load_lds(
      (const __attribute__((address_space(1))) void*)g,
      (__attribute__((address_space(3))) void*)(unsigned)(uintptr_t)l,
      16, 0, 0);
}

// ---------------------------------------------------------------------------
// K1a (R15): row-parallel norms + tanh leaves + weight tail. 4 blocks/bag,
// 16 rows each -> 2048 blocks (8/CU) so pass 1 streams at full parallelism
// instead of being barrier-chained with passes 2/3 inside a per-bag block
// (R12-R14 all pinned at ~105us due to that serialized 3-pass structure).
// Per-row reduction is wave-internal and bitwise-identical to the proven
// ordering regardless of row->wave mapping.
// ---------------------------------------------------------------------------
__global__ __launch_bounds__(256) void k_prep_a(const float* __restrict__ rep,
                                                float* __restrict__ inv_g,
                                                __hip_bfloat16* __restrict__ tfeats,
                                                const float* __restrict__ w1,
                                                __hip_bfloat16* __restrict__ w1b,
                                                const float* __restrict__ w2,
                                                __hip_bfloat16* __restrict__ w2b) {
  int blk = blockIdx.x;
  int b = blk >> 2, qr = blk & 3;
  const float* bag = rep + (size_t)b * NPB * DIM;
  int t = threadIdx.x, wave = t >> 6, lane = t & 63;

  #pragma unroll
  for (int r = 0; r < 4; r++) {
    int n = qr * 16 + wave * 4 + r;
    const float* x = bag + (size_t)n * DIM;
    float f[16];
    #pragma unroll
    for (int k = 0; k < 16; k++) f[k] = x[lane + 64 * k];
    float acc = 0.f;
    #pragma unroll
    for (int k = 0; k < 16; k++) acc += f[k] * f[k];
    __hip_bfloat16* tr = tfeats + ((((size_t)b << 6) + n) << 10);
    #pragma unroll
    for (int k = 0; k < 16; k++) {
      short o = bf16bits(fast_tanh(f[k]));
      tr[lane + 64 * k] = *reinterpret_cast<__hip_bfloat16*>(&o);
    }
    for (int off = 32; off; off >>= 1) acc += __shfl_xor(acc, off);
    if (lane == 0) inv_g[b * 64 + n] = 1.0f / sqrtf(acc);
  }

  // ---- fused weight conversion tail (elementwise -> mapping-independent)
  {
    const int nv1 = (DIM * 2 * DIM) / 4;
    const int nv2 = (DIM * DIM) / 4;
    for (int i = blk * 256 + t; i < nv1 + nv2; i += 2048 * 256) {
      if (i < nv1) {
        f32x4 v = ((const f32x4*)w1)[i];
        short4v o;
        o.x = bf16bits(v.x); o.y = bf16bits(v.y);
        o.z = bf16bits(v.z); o.w = bf16bits(v.w);
        ((short4v*)w1b)[i] = o;
      } else {
        f32x4 v = ((const f32x4*)w2)[i - nv1];
        short4v o;
        o.x = bf16bits(v.x); o.y = bf16bits(v.y);
        o.z = bf16bits(v.z); o.w = bf16bits(v.w);
        ((short4v*)w2b)[i - nv1] = o;
      }
    }
  }
}

// ---------------------------------------------------------------------------
// K1b (R15): per-bag S (pass 2), dist (pass 3), softmax -> nw. Exact proven
// summation orders; inv_n comes from k_prep_a via global.
// ---------------------------------------------------------------------------
__global__ __launch_bounds__(1024) void k_prep_b(const float* __restrict__ rep,
                                                 const float* __restrict__ inv_g,
                                                 float* __restrict__ nw) {
  int b = blockIdx.x;
  const float* bag = rep + (size_t)b * NPB * DIM;
  __shared__ float inv_n[NPB];
  __shared__ float dist[NPB];
  __shared__ alignas(16) float S[DIM];
  int t = threadIdx.x, wave = t >> 6, lane = t & 63;

  if (t < 64) inv_n[t] = inv_g[b * 64 + t];
  __syncthreads();

  // ---- pass 2: S, vectorized across columns; per-column n-order unchanged
  if (t < 256) {
    const f32x4* br = (const f32x4*)bag;
    f32x4 acc = (f32x4){0.f, 0.f, 0.f, 0.f};
    #pragma unroll 16
    for (int n = 0; n < NPB; n++) {
      f32x4 v = br[n * 256 + t];
      float w = inv_n[n];
      acc.x += v.x * w; acc.y += v.y * w;
      acc.z += v.z * w; acc.w += v.w * w;
    }
    ((f32x4*)S)[t] = acc;
  }
  __syncthreads();

  // ---- pass 3: dist, strided scalar loads, exact-order dot with S
  for (int n = wave; n < NPB; n += 16) {
    const float* x = bag + (size_t)n * DIM;
    float f[16];
    #pragma unroll
    for (int k = 0; k < 16; k++) f[k] = x[lane + 64 * k];
    float acc = 0.f;
    #pragma unroll
    for (int k = 0; k < 16; k++) acc += f[k] * S[lane + 64 * k];
    for (int off = 32; off; off >>= 1) acc += __shfl_xor(acc, off);
    if (lane == 0) dist[n] = acc * inv_n[n];
  }
  __syncthreads();

  if (t < 64) {
    float v = dist[t], m = v;
    for (int off = 32; off; off >>= 1) m = fmaxf(m, __shfl_xor(m, off));
    float e = expf(v - m), s = e;
    for (int off = 32; off; off >>= 1) s += __shfl_xor(s, off);
    nw[b * NPB + t] = e / s;
  }
}

// ---------------------------------------------------------------------------
// K2: per-bag Huffman merge order + level. 4 bags per block.
// ---------------------------------------------------------------------------
__global__ __launch_bounds__(256) void k_merge_levels(const float* __restrict__ nw,
                                                      unsigned* __restrict__ lvlbuf,
                                                      unsigned* __restrict__ cnt) {
  int b = blockIdx.x * 4 + (threadIdx.x >> 6);
  int lane = threadIdx.x & 63;
  const float INF = __int_as_float(0x7f800000);
  float w = nw[b * NPB + lane];
  bool alive = true;
  int ready = 0;
  int mycnt = 0;

  for (int t = 0; t < NSTEP; t++) {
    float v = alive ? w : INF; int i = lane;
    for (int off = 32; off; off >>= 1) {
      float v2 = __shfl_xor(v, off); int j2 = __shfl_xor(i, off);
      if (v2 < v || (v2 == v && j2 < i)) { v = v2; i = j2; }
    }
    int i1 = i;
    float vv = (alive && lane != i1) ? w : INF; int ii = lane;
    for (int off = 32; off; off >>= 1) {
      float v2 = __shfl_xor(vv, off); int j2 = __shfl_xor(ii, off);
      if (v2 < vv || (v2 == vv && j2 < ii)) { vv = v2; ii = j2; }
    }
    int i2 = ii;
    float w1v = __shfl(w, i1), w2v = __shfl(w, i2);
    if (lane == i1) w = w1v + w2v;
    if (lane == i2) alive = false;
    int r1 = __shfl(ready, i1), r2 = __shfl(ready, i2);
    int lvl = max(r1, r2) + 1;
    int rank = __shfl(mycnt, lvl - 1);
    if (lane == lvl - 1) mycnt++;
    if (lane == i1) ready = lvl;
    if (lane == 0)
      lvlbuf[b * NSTEP + t] = (unsigned)i1 | ((unsigned)i2 << 6) |
                              ((unsigned)lvl << 12) | ((unsigned)rank << 18);
  }
  cnt[b * 64 + lane] = (unsigned)mycnt;
}

// K3: per-level exclusive scan over bags
__global__ __launch_bounds__(512) void k_bagscan(const unsigned* __restrict__ cnt,
                                                 unsigned* __restrict__ bagoff,
                                                 unsigned* __restrict__ levtot) {
  int l = blockIdx.x + 1;
  int b = threadIdx.x;
  __shared__ unsigned s[512];
  unsigned v = cnt[b * 64 + (l - 1)];
  s[b] = v; __syncthreads();
  for (int o = 1; o < 512; o <<= 1) {
    unsigned x = (b >= o) ? s[b - o] : 0u; __syncthreads();
    s[b] += x; __syncthreads();
  }
  bagoff[l * 512 + b] = s[b] - v;
  if (b == 511) levtot[l] = s[511];
}

// K5: scatter merges into level-sorted worklist (fused level-offset scan).
__global__ __launch_bounds__(256) void k_scatter(const unsigned* __restrict__ lvlbuf,
                                                 const unsigned* __restrict__ levtot,
                                                 const unsigned* __restrict__ bagoff,
                                                 unsigned* __restrict__ wl,
                                                 unsigned* __restrict__ off_out) {
  __shared__ unsigned off_s[65];
  int t = threadIdx.x;
  if (t < 64) {
    unsigned v = (t >= 1) ? levtot[t] : 0u;
    unsigned x = v;
    for (int o = 1; o < 64; o <<= 1) {
      unsigned y = __shfl_up(x, o);
      if (t >= o) x += y;
    }
    off_s[t] = x - v;
    if (t == 63) off_s[64] = x;
    if (blockIdx.x == 0) {
      off_out[t] = x - v;
      if (t == 63) off_out[64] = x;
    }
  }
  __syncthreads();

  int idx = blockIdx.x * 256 + t;
  int b = idx / NSTEP, st = idx % NSTEP;
  unsigned e = lvlbuf[idx];
  unsigned i1 = e & 63, i2 = (e >> 6) & 63, lvl = (e >> 12) & 63, rank = (e >> 18) & 31;
  unsigned pos = off_s[lvl] + bagoff[lvl * 512 + b] + rank;
  wl[pos] = (unsigned)b | (i1 << 9) | (i2 << 15) | ((st == NSTEP - 1 ? 1u : 0u) << 21);
}

// ---------------------------------------------------------------------------
// K7: batched MFMA GEMM for one level. BM=256 x BN=128, BK=64, 8 waves,
// wave-tile 64x64 (4M x 2N). Proven R11 body (bit-exact outputs).
// ---------------------------------------------------------------------------
template <int KTOT, bool FC1>
__global__ __launch_bounds__(512) void k_fc(const __hip_bfloat16* __restrict__ Asrc,
                                            const __hip_bfloat16* __restrict__ wB,
                                            const float* __restrict__ bias,
                                            const unsigned* __restrict__ wl,
                                            const unsigned* __restrict__ off,
                                            __hip_bfloat16* __restrict__ hbuf,
                                            __hip_bfloat16* __restrict__ tfeats,
                                            float* __restrict__ rootfeat,
                                            int level) {
  __shared__ alignas(16) short As[256 * 64];   // 32 KB
  __shared__ alignas(16) short Bs[128 * 64];   // 16 KB
  __shared__ unsigned wle[256];

  int nwg = (int)gridDim.x;
  int hw = (int)blockIdx.x;
  int q = nwg >> 3, r = nwg & 7;
  int xcd = hw & 7, ii = hw >> 3;
  int wid = (xcd < r ? xcd * (q + 1) : r * (q + 1) + (xcd - r) * q) + ii;
  int nbase = (wid & 7) * 128;     // 8 N-panels of 128
  int mbase = (wid >> 3) * 256;    // M-tiles of 256

  int c0 = (int)off[level];
  int count = (int)off[level + 1] - c0;
  if (mbase >= count) return;
  int t = threadIdx.x, wv = t >> 6, lane = t & 63;
  if (t < 256) wle[t] = wl[c0 + min(mbase + t, count - 1)];
  __syncthreads();

  int lr = lane >> 3, p = lane & 7;
  const __hip_bfloat16* aptrA[4];
  const __hip_bfloat16* aptrB[4];
  const __hip_bfloat16* bptr[2];
  #pragma unroll
  for (int c = 0; c < 4; c++) {
    int rc = (wv * 4 + c) * 8 + lr;    // 0..255: A-row this lane stages
    int u = p ^ (rc & 7);
    if (FC1) {
      unsigned e = wle[rc];
      int bidx = e & 511, s1 = (e >> 9) & 63, s2 = (e >> 15) & 63;
      aptrA[c] = Asrc + (((size_t)(bidx << 6) + s1) << 10) + (u << 3);
      aptrB[c] = Asrc + (((size_t)(bidx << 6) + s2) << 10) + (u << 3);
    } else {
      aptrA[c] = Asrc + ((size_t)(mbase + rc) << 10) + (u << 3);
      aptrB[c] = aptrA[c];
    }
  }
  #pragma unroll
  for (int c = 0; c < 2; c++) {
    int rc = (wv * 2 + c) * 8 + lr;    // 0..127: B-row this lane stages
    int u = p ^ (rc & 7);
    bptr[c] = wB + (size_t)(nbase + rc) * KTOT + (u << 3);
  }

  f32x4 acc[4][4];
  #pragma unroll
  for (int i = 0; i < 4; i++)
    #pragma unroll
    for (int j = 0; j < 4; j++) acc[i][j] = (f32x4){0.f, 0.f, 0.f, 0.f};

  int mh = wv >> 1, nh = wv & 1;       // 4M x 2N wave grid

  for (int k0 = 0; k0 < KTOT; k0 += 64) {
    #pragma unroll
    for (int c = 0; c < 4; c++) {
      int ch = wv * 4 + c;             // 0..31 A-chunks (8 rows each)
      const __hip_bfloat16* g =
          (FC1 && k0 >= DIM) ? (aptrB[c] + (k0 - DIM)) : (aptrA[c] + k0);
      gld16(g, &As[ch << 9]);
    }
    #pragma unroll
    for (int c = 0; c < 2; c++) {
      int ch = wv * 2 + c;             // 0..15 B-chunks
      gld16(bptr[c] + k0, &Bs[ch << 9]);
    }
    __syncthreads();
    #pragma unroll
    for (int kc = 0; kc < 2; kc++) {
      short8 a[4], bb[4];
      #pragma unroll
      for (int mi = 0; mi < 4; mi++) {
        int rr = mh * 64 + mi * 16 + (lane & 15);
        int u = (kc * 4 + (lane >> 4)) ^ (rr & 7);
        a[mi] = *(const short8*)&As[rr * 64 + u * 8];
      }
      #pragma unroll
      for (int ni = 0; ni < 4; ni++) {
        int rr = nh * 64 + ni * 16 + (lane & 15);
        int u = (kc * 4 + (lane >> 4)) ^ (rr & 7);
        bb[ni] = *(const short8*)&Bs[rr * 64 + u * 8];
      }
      #pragma unroll
      for (int mi = 0; mi < 4; mi++)
        #pragma unroll
        for (int ni = 0; ni < 4; ni++)
          acc[mi][ni] = __builtin_amdgcn_mfma_f32_16x16x32_bf16(a[mi], bb[ni],
                                                                acc[mi][ni], 0, 0, 0);
    }
    __syncthreads();
  }

  #pragma unroll
  for (int mi = 0; mi < 4; mi++) {
    #pragma unroll
    for (int reg = 0; reg < 4; reg++) {
      int m_loc = mh * 64 + mi * 16 + ((lane >> 4) << 2) + reg;
      int m = mbase + m_loc;
      if (m >= count) continue;
      #pragma unroll
      for (int ni = 0; ni < 4; ni++) {
        int n = nbase + nh * 64 + ni * 16 + (lane & 15);
        float v = acc[mi][ni][reg] + bias[n];
        if (FC1) {
          hbuf[(size_t)m * DIM + n] = __float2bfloat16(fast_tanh(v));
        } else {
          unsigned e = wle[m_loc];
          int bidx = e & 511, d = (e >> 9) & 63;
          tfeats[(((size_t)(bidx << 6) + d) << 10) + n] = __float2bfloat16(fast_tanh(v));
          if (e >> 21) rootfeat[(size_t)bidx * DIM + n] = v;
        }
      }
    }
  }
}

// ---------------------------------------------------------------------------
// K7b: deep-level fallback (> LMAX) + fused final scores. One block per bag.
// ---------------------------------------------------------------------------
#define XP(i) ((i) + ((i) >> 3))
__global__ __launch_bounds__(1024) void k_deep(__hip_bfloat16* __restrict__ tfeats,
                                               const __hip_bfloat16* __restrict__ w1b,
                                               const float* __restrict__ b1,
                                               const __hip_bfloat16* __restrict__ w2b,
                                               const float* __restrict__ b2,
                                               const unsigned* __restrict__ lvlbuf,
                                               float* __restrict__ rootfeat,
                                               const float* __restrict__ rel,
                                               float* __restrict__ out) {
  int b = blockIdx.x;
  __shared__ float xs[XP(2048) + 1];
  __shared__ float hs[XP(1024) + 1];
  __shared__ unsigned steps[NSTEP];
  int t = threadIdx.x, wv = t >> 6, lane = t & 63;
  if (t < NSTEP) steps[t] = lvlbuf[b * NSTEP + t];
  __syncthreads();

  for (int s = 0; s < NSTEP; s++) {
    unsigned e = steps[s];
    int lvl = (int)((e >> 12) & 63);
    if (lvl <= LMAX) continue;
    int i1 = (int)(e & 63), i2 = (int)((e >> 6) & 63);
    const __hip_bfloat16* r1 = tfeats + ((((size_t)b << 6) + i1) << 10);
    const __hip_bfloat16* r2 = tfeats + ((((size_t)b << 6) + i2) << 10);
    xs[XP(t)] = __bfloat162float(r1[t]);
    xs[XP(1024 + t)] = __bfloat162float(r2[t]);
    __syncthreads();
    for (int r = 0; r < 64; r++) {
      int n = r * 16 + wv;
      const short8* wr = (const short8*)(w1b + (size_t)n * 2048);
      float acc = 0.f;
      for (int c = lane; c < 256; c += 64) {
        short8 w8 = wr[c];
        #pragma unroll
        for (int j = 0; j < 8; j++) {
          float wf = __uint_as_float(((unsigned)(unsigned short)w8[j]) << 16);
          acc += xs[XP(c * 8 + j)] * wf;
        }
      }
      for (int off = 32; off; off >>= 1) acc += __shfl_xor(acc, off);
      if (lane == 0) hs[XP(n)] = fast_tanh(acc + b1[n]);
    }
    __syncthreads();
    for (int r = 0; r < 64; r++) {
      int n = r * 16 + wv;
      const short8* wr = (const short8*)(w2b + (size_t)n * 1024);
      float acc = 0.f;
      for (int c = lane; c < 128; c += 64) {
        short8 w8 = wr[c];
        #pragma unroll
        for (int j = 0; j < 8; j++) {
          float wf = __uint_as_float(((unsigned)(unsigned short)w8[j]) << 16);
          acc += hs[XP(c * 8 + j)] * wf;
        }
      }
      for (int off = 32; off; off >>= 1) acc += __shfl_xor(acc, off);
      if (lane == 0) {
        float f = acc + b2[n];
        tfeats[((((size_t)b << 6) + i1) << 10) + n] = __float2bfloat16(fast_tanh(f));
        if (s == NSTEP - 1) rootfeat[(size_t)b * DIM + n] = f;
      }
    }
    __syncthreads();
  }

  // ---- fused scores: sigmoid(rootfeat[b] @ rel^T)
  __shared__ float fr[DIM];
  fr[t] = rootfeat[(size_t)b * DIM + t];
  __syncthreads();
  for (int c = wv; c < NCLS; c += 16) {
    const float* w = rel + (size_t)c * DIM;
    float acc = 0.f;
    for (int j = lane; j < DIM; j += 64) acc += fr[j] * w[j];
    for (int off = 32; off; off >>= 1) acc += __shfl_xor(acc, off);
    if (lane == 0) out[b * NCLS + c] = 1.0f / (1.0f + expf(-acc));
  }
}

// ---------------------------------------------------------------------------
extern "C" void kernel_launch(void* const* d_in, const int* in_sizes, int n_in,
                              void* d_out, int out_size, void* d_ws, size_t ws_size,
                              hipStream_t stream) {
  const float* rep = (const float*)d_in[0];
  const float* w1  = (const float*)d_in[1];
  const float* b1  = (const float*)d_in[2];
  const float* w2  = (const float*)d_in[3];
  const float* b2  = (const float*)d_in[4];
  const float* rel = (const float*)d_in[5];
  float* out = (float*)d_out;

  char* ws = (char*)d_ws;
  __hip_bfloat16* tfeats = (__hip_bfloat16*)ws; ws += (size_t)NBAG * NPB * DIM * 2;
  __hip_bfloat16* hbuf   = (__hip_bfloat16*)ws; ws += (size_t)MAXROWS * DIM * 2;
  __hip_bfloat16* w1b    = (__hip_bfloat16*)ws; ws += (size_t)DIM * 2 * DIM * 2;
  __hip_bfloat16* w2b    = (__hip_bfloat16*)ws; ws += (size_t)DIM * DIM * 2;
  float* rootfeat        = (float*)ws;          ws += (size_t)NBAG * DIM * 4;
  float* nw              = (float*)ws;          ws += (size_t)NBAG * NPB * 4;
  float* inv_g           = (float*)ws;          ws += (size_t)NBAG * NPB * 4;
  unsigned* lvlbuf       = (unsigned*)ws;       ws += (size_t)NBAG * NSTEP * 4;
  unsigned* cnt          = (unsigned*)ws;       ws += (size_t)NBAG * 64 * 4;
  unsigned* bagoff       = (unsigned*)ws;       ws += (size_t)64 * 512 * 4;
  unsigned* levtot       = (unsigned*)ws;       ws += 64 * 4;
  unsigned* off          = (unsigned*)ws;       ws += 128 * 4;
  unsigned* wl           = (unsigned*)ws;       ws += (size_t)NBAG * NSTEP * 4;

  k_prep_a<<<NBAG * 4, 256, 0, stream>>>(rep, inv_g, tfeats, w1, w1b, w2, w2b);
  k_prep_b<<<NBAG, 1024, 0, stream>>>(rep, inv_g, nw);
  k_merge_levels<<<NBAG / 4, 256, 0, stream>>>(nw, lvlbuf, cnt);
  k_bagscan<<<63, 512, 0, stream>>>(cnt, bagoff, levtot);
  k_scatter<<<126, 256, 0, stream>>>(lvlbuf, levtot, bagoff, wl, off);

  for (int l = 1; l <= LMAX; l++) {
    int cap = 64 / (l + 1); if (cap > 32) cap = 32;
    int capM = 2 * cap;                       // 256-row M-tiles capacity
    k_fc<2 * DIM, true><<<dim3(8 * capM), 512, 0, stream>>>(
        tfeats, w1b, b1, wl, off, hbuf, nullptr, nullptr, l);
    k_fc<DIM, false><<<dim3(8 * capM), 512, 0, stream>>>(
        hbuf, w2b, b2, wl, off, nullptr, tfeats, rootfeat, l);
  }
  k_deep<<<NBAG, 1024, 0, stream>>>(tfeats, w1b, b1, w2b, b2, lvlbuf, rootfeat,
                                    rel, out);
}

// Round 5
// 785.114 us; speedup vs baseline: 1.0429x; 1.0413x over previous
//
#include <hip/hip_runtime.h>
#include <hip/hip_bf16.h>
#include <math.h>

#define NBAG 512
#define NPB 64
#define DIM 1024
#define NCLS 53
#define NSTEP 63
#define MAXROWS 16384  // level-1 worst case: 512 bags * 32 merges
#define LMAX 8         // levels 1..LMAX via batched GEMM; deeper via k_deep
                       // (measured: LMAX=4 -> k_deep 1391us; LMAX=14 -> +12 launches, +95us;
                       //  8-phase k_fc8 port for l<=2 -> +72us, reverted)

typedef __attribute__((ext_vector_type(8))) short short8;
typedef __attribute__((ext_vector_type(4))) short short4v;
typedef __attribute__((ext_vector_type(4))) float f32x4;
typedef unsigned long long u64;

__device__ __forceinline__ short bf16bits(float x) {
  __hip_bfloat16 h = __float2bfloat16(x);
  return *reinterpret_cast<short*>(&h);
}

// fast tanh: 1 - 2/(e^{2x}+1). Feature path only — never in the node-weight
// computation (tree order must not change).
__device__ __forceinline__ float fast_tanh(float x) {
  float e = __expf(2.0f * x);
  return 1.0f - __fdividef(2.0f, e + 1.0f);
}

// global -> LDS direct copy, 16B per lane, dest = wave-uniform base + lane*16
__device__ __forceinline__ void gld16(const void* g, void* l) {
  __builtin_amdgcn_global_load_lds(
      (const __attribute__((address_space(1))) void*)g,
      (__attribute__((address_space(3))) void*)(unsigned)(uintptr_t)l,
      16, 0, 0);
}

// ---------------------------------------------------------------------------
// K1a (R15): row-parallel norms + tanh leaves + weight tail. 4 blocks/bag,
// 16 rows each -> 2048 blocks (8/CU) so pass 1 streams at full parallelism.
// Per-row reduction is wave-internal and bitwise-identical to the proven
// ordering regardless of row->wave mapping.
// ---------------------------------------------------------------------------
__global__ __launch_bounds__(256) void k_prep_a(const float* __restrict__ rep,
                                                float* __restrict__ inv_g,
                                                __hip_bfloat16* __restrict__ tfeats,
                                                const float* __restrict__ w1,
                                                __hip_bfloat16* __restrict__ w1b,
                                                const float* __restrict__ w2,
                                                __hip_bfloat16* __restrict__ w2b) {
  int blk = blockIdx.x;
  int b = blk >> 2, qr = blk & 3;
  const float* bag = rep + (size_t)b * NPB * DIM;
  int t = threadIdx.x, wave = t >> 6, lane = t & 63;

  #pragma unroll
  for (int r = 0; r < 4; r++) {
    int n = qr * 16 + wave * 4 + r;
    const float* x = bag + (size_t)n * DIM;
    float f[16];
    #pragma unroll
    for (int k = 0; k < 16; k++) f[k] = x[lane + 64 * k];
    float acc = 0.f;
    #pragma unroll
    for (int k = 0; k < 16; k++) acc += f[k] * f[k];
    __hip_bfloat16* tr = tfeats + ((((size_t)b << 6) + n) << 10);
    #pragma unroll
    for (int k = 0; k < 16; k++) {
      short o = bf16bits(fast_tanh(f[k]));
      tr[lane + 64 * k] = *reinterpret_cast<__hip_bfloat16*>(&o);
    }
    for (int off = 32; off; off >>= 1) acc += __shfl_xor(acc, off);
    if (lane == 0) inv_g[b * 64 + n] = 1.0f / sqrtf(acc);
  }

  // ---- fused weight conversion tail (elementwise -> mapping-independent)
  {
    const int nv1 = (DIM * 2 * DIM) / 4;
    const int nv2 = (DIM * DIM) / 4;
    for (int i = blk * 256 + t; i < nv1 + nv2; i += 2048 * 256) {
      if (i < nv1) {
        f32x4 v = ((const f32x4*)w1)[i];
        short4v o;
        o.x = bf16bits(v.x); o.y = bf16bits(v.y);
        o.z = bf16bits(v.z); o.w = bf16bits(v.w);
        ((short4v*)w1b)[i] = o;
      } else {
        f32x4 v = ((const f32x4*)w2)[i - nv1];
        short4v o;
        o.x = bf16bits(v.x); o.y = bf16bits(v.y);
        o.z = bf16bits(v.z); o.w = bf16bits(v.w);
        ((short4v*)w2b)[i - nv1] = o;
      }
    }
  }
}

// ---------------------------------------------------------------------------
// K1b (R15): per-bag S (pass 2), dist (pass 3), softmax -> nw. Exact proven
// summation orders; inv_n comes from k_prep_a via global.
// ---------------------------------------------------------------------------
__global__ __launch_bounds__(1024) void k_prep_b(const float* __restrict__ rep,
                                                 const float* __restrict__ inv_g,
                                                 float* __restrict__ nw) {
  int b = blockIdx.x;
  const float* bag = rep + (size_t)b * NPB * DIM;
  __shared__ float inv_n[NPB];
  __shared__ float dist[NPB];
  __shared__ alignas(16) float S[DIM];
  int t = threadIdx.x, wave = t >> 6, lane = t & 63;

  if (t < 64) inv_n[t] = inv_g[b * 64 + t];
  __syncthreads();

  // ---- pass 2: S, vectorized across columns; per-column n-order unchanged
  if (t < 256) {
    const f32x4* br = (const f32x4*)bag;
    f32x4 acc = (f32x4){0.f, 0.f, 0.f, 0.f};
    #pragma unroll 16
    for (int n = 0; n < NPB; n++) {
      f32x4 v = br[n * 256 + t];
      float w = inv_n[n];
      acc.x += v.x * w; acc.y += v.y * w;
      acc.z += v.z * w; acc.w += v.w * w;
    }
    ((f32x4*)S)[t] = acc;
  }
  __syncthreads();

  // ---- pass 3: dist, strided scalar loads, exact-order dot with S
  for (int n = wave; n < NPB; n += 16) {
    const float* x = bag + (size_t)n * DIM;
    float f[16];
    #pragma unroll
    for (int k = 0; k < 16; k++) f[k] = x[lane + 64 * k];
    float acc = 0.f;
    #pragma unroll
    for (int k = 0; k < 16; k++) acc += f[k] * S[lane + 64 * k];
    for (int off = 32; off; off >>= 1) acc += __shfl_xor(acc, off);
    if (lane == 0) dist[n] = acc * inv_n[n];
  }
  __syncthreads();

  if (t < 64) {
    float v = dist[t], m = v;
    for (int off = 32; off; off >>= 1) m = fmaxf(m, __shfl_xor(m, off));
    float e = expf(v - m), s = e;
    for (int off = 32; off; off >>= 1) s += __shfl_xor(s, off);
    nw[b * NPB + t] = e / s;
  }
}

// ---------------------------------------------------------------------------
// K2 (R16): per-bag Huffman merge order + level. 4 bags per block.
// Packed-key two-smallest butterfly: key = [63:32]=w_bits (positive floats
// order like their bits), [11:6]=lane (reference tie-break), [5:0]=ready;
// dead lanes = ~0. One 6-stage reduction tracking (k1,k2) replaces the two
// sequential argmin butterflies AND the w/ready broadcast shuffles (all
// fields are carried in the key). Selection, sums, lvl/rank bookkeeping are
// bitwise-identical to the proven two-pass version (R4-R15 lineage):
// lex-min (w, lane) == u64 min of key; duplicate of w[i1] lands in k2
// exactly as exclude-i1 argmin would.
// ---------------------------------------------------------------------------
__global__ __launch_bounds__(256) void k_merge_levels(const float* __restrict__ nw,
                                                      unsigned* __restrict__ lvlbuf,
                                                      unsigned* __restrict__ cnt) {
  int b = blockIdx.x * 4 + (threadIdx.x >> 6);
  int lane = threadIdx.x & 63;
  float w = nw[b * NPB + lane];
  bool alive = true;
  int ready = 0;
  int mycnt = 0;

  for (int t = 0; t < NSTEP; t++) {
    u64 k1 = alive ? (((u64)__float_as_uint(w) << 32) |
                      ((unsigned)lane << 6) | (unsigned)ready)
                   : ~0ull;
    u64 k2 = ~0ull;
    #pragma unroll
    for (int off = 32; off; off >>= 1) {
      u64 o1 = __shfl_xor(k1, off);
      u64 o2 = __shfl_xor(k2, off);
      if (o1 < k1) {
        k2 = (k1 < o2) ? k1 : o2;
        k1 = o1;
      } else {
        k2 = (o1 < k2) ? o1 : k2;
      }
    }
    int i1 = (int)(k1 >> 6) & 63;
    int i2 = (int)(k2 >> 6) & 63;
    float w1v = __uint_as_float((unsigned)(k1 >> 32));
    float w2v = __uint_as_float((unsigned)(k2 >> 32));
    int r1 = (int)(k1 & 63u);
    int r2 = (int)(k2 & 63u);
    int lvl = max(r1, r2) + 1;
    int rank = __shfl(mycnt, lvl - 1);
    if (lane == lvl - 1) mycnt++;
    if (lane == i1) { w = w1v + w2v; ready = lvl; }
    if (lane == i2) alive = false;
    if (lane == 0)
      lvlbuf[b * NSTEP + t] = (unsigned)i1 | ((unsigned)i2 << 6) |
                              ((unsigned)lvl << 12) | ((unsigned)rank << 18);
  }
  cnt[b * 64 + lane] = (unsigned)mycnt;
}

// K3: per-level exclusive scan over bags
__global__ __launch_bounds__(512) void k_bagscan(const unsigned* __restrict__ cnt,
                                                 unsigned* __restrict__ bagoff,
                                                 unsigned* __restrict__ levtot) {
  int l = blockIdx.x + 1;
  int b = threadIdx.x;
  __shared__ unsigned s[512];
  unsigned v = cnt[b * 64 + (l - 1)];
  s[b] = v; __syncthreads();
  for (int o = 1; o < 512; o <<= 1) {
    unsigned x = (b >= o) ? s[b - o] : 0u; __syncthreads();
    s[b] += x; __syncthreads();
  }
  bagoff[l * 512 + b] = s[b] - v;
  if (b == 511) levtot[l] = s[511];
}

// K5: scatter merges into level-sorted worklist (fused level-offset scan).
__global__ __launch_bounds__(256) void k_scatter(const unsigned* __restrict__ lvlbuf,
                                                 const unsigned* __restrict__ levtot,
                                                 const unsigned* __restrict__ bagoff,
                                                 unsigned* __restrict__ wl,
                                                 unsigned* __restrict__ off_out) {
  __shared__ unsigned off_s[65];
  int t = threadIdx.x;
  if (t < 64) {
    unsigned v = (t >= 1) ? levtot[t] : 0u;
    unsigned x = v;
    for (int o = 1; o < 64; o <<= 1) {
      unsigned y = __shfl_up(x, o);
      if (t >= o) x += y;
    }
    off_s[t] = x - v;
    if (t == 63) off_s[64] = x;
    if (blockIdx.x == 0) {
      off_out[t] = x - v;
      if (t == 63) off_out[64] = x;
    }
  }
  __syncthreads();

  int idx = blockIdx.x * 256 + t;
  int b = idx / NSTEP, st = idx % NSTEP;
  unsigned e = lvlbuf[idx];
  unsigned i1 = e & 63, i2 = (e >> 6) & 63, lvl = (e >> 12) & 63, rank = (e >> 18) & 31;
  unsigned pos = off_s[lvl] + bagoff[lvl * 512 + b] + rank;
  wl[pos] = (unsigned)b | (i1 << 9) | (i2 << 15) | ((st == NSTEP - 1 ? 1u : 0u) << 21);
}

// ---------------------------------------------------------------------------
// K7: batched MFMA GEMM for one level. BM=256 x BN=128, BK=64, 8 waves,
// wave-tile 64x64 (4M x 2N). Proven R11 body (bit-exact outputs).
// ---------------------------------------------------------------------------
template <int KTOT, bool FC1>
__global__ __launch_bounds__(512) void k_fc(const __hip_bfloat16* __restrict__ Asrc,
                                            const __hip_bfloat16* __restrict__ wB,
                                            const float* __restrict__ bias,
                                            const unsigned* __restrict__ wl,
                                            const unsigned* __restrict__ off,
                                            __hip_bfloat16* __restrict__ hbuf,
                                            __hip_bfloat16* __restrict__ tfeats,
                                            float* __restrict__ rootfeat,
                                            int level) {
  __shared__ alignas(16) short As[256 * 64];   // 32 KB
  __shared__ alignas(16) short Bs[128 * 64];   // 16 KB
  __shared__ unsigned wle[256];

  int nwg = (int)gridDim.x;
  int hw = (int)blockIdx.x;
  int q = nwg >> 3, r = nwg & 7;
  int xcd = hw & 7, ii = hw >> 3;
  int wid = (xcd < r ? xcd * (q + 1) : r * (q + 1) + (xcd - r) * q) + ii;
  int nbase = (wid & 7) * 128;     // 8 N-panels of 128
  int mbase = (wid >> 3) * 256;    // M-tiles of 256

  int c0 = (int)off[level];
  int count = (int)off[level + 1] - c0;
  if (mbase >= count) return;
  int t = threadIdx.x, wv = t >> 6, lane = t & 63;
  if (t < 256) wle[t] = wl[c0 + min(mbase + t, count - 1)];
  __syncthreads();

  int lr = lane >> 3, p = lane & 7;
  const __hip_bfloat16* aptrA[4];
  const __hip_bfloat16* aptrB[4];
  const __hip_bfloat16* bptr[2];
  #pragma unroll
  for (int c = 0; c < 4; c++) {
    int rc = (wv * 4 + c) * 8 + lr;    // 0..255: A-row this lane stages
    int u = p ^ (rc & 7);
    if (FC1) {
      unsigned e = wle[rc];
      int bidx = e & 511, s1 = (e >> 9) & 63, s2 = (e >> 15) & 63;
      aptrA[c] = Asrc + (((size_t)(bidx << 6) + s1) << 10) + (u << 3);
      aptrB[c] = Asrc + (((size_t)(bidx << 6) + s2) << 10) + (u << 3);
    } else {
      aptrA[c] = Asrc + ((size_t)(mbase + rc) << 10) + (u << 3);
      aptrB[c] = aptrA[c];
    }
  }
  #pragma unroll
  for (int c = 0; c < 2; c++) {
    int rc = (wv * 2 + c) * 8 + lr;    // 0..127: B-row this lane stages
    int u = p ^ (rc & 7);
    bptr[c] = wB + (size_t)(nbase + rc) * KTOT + (u << 3);
  }

  f32x4 acc[4][4];
  #pragma unroll
  for (int i = 0; i < 4; i++)
    #pragma unroll
    for (int j = 0; j < 4; j++) acc[i][j] = (f32x4){0.f, 0.f, 0.f, 0.f};

  int mh = wv >> 1, nh = wv & 1;       // 4M x 2N wave grid

  for (int k0 = 0; k0 < KTOT; k0 += 64) {
    #pragma unroll
    for (int c = 0; c < 4; c++) {
      int ch = wv * 4 + c;             // 0..31 A-chunks (8 rows each)
      const __hip_bfloat16* g =
          (FC1 && k0 >= DIM) ? (aptrB[c] + (k0 - DIM)) : (aptrA[c] + k0);
      gld16(g, &As[ch << 9]);
    }
    #pragma unroll
    for (int c = 0; c < 2; c++) {
      int ch = wv * 2 + c;             // 0..15 B-chunks
      gld16(bptr[c] + k0, &Bs[ch << 9]);
    }
    __syncthreads();
    #pragma unroll
    for (int kc = 0; kc < 2; kc++) {
      short8 a[4], bb[4];
      #pragma unroll
      for (int mi = 0; mi < 4; mi++) {
        int rr = mh * 64 + mi * 16 + (lane & 15);
        int u = (kc * 4 + (lane >> 4)) ^ (rr & 7);
        a[mi] = *(const short8*)&As[rr * 64 + u * 8];
      }
      #pragma unroll
      for (int ni = 0; ni < 4; ni++) {
        int rr = nh * 64 + ni * 16 + (lane & 15);
        int u = (kc * 4 + (lane >> 4)) ^ (rr & 7);
        bb[ni] = *(const short8*)&Bs[rr * 64 + u * 8];
      }
      #pragma unroll
      for (int mi = 0; mi < 4; mi++)
        #pragma unroll
        for (int ni = 0; ni < 4; ni++)
          acc[mi][ni] = __builtin_amdgcn_mfma_f32_16x16x32_bf16(a[mi], bb[ni],
                                                                acc[mi][ni], 0, 0, 0);
    }
    __syncthreads();
  }

  #pragma unroll
  for (int mi = 0; mi < 4; mi++) {
    #pragma unroll
    for (int reg = 0; reg < 4; reg++) {
      int m_loc = mh * 64 + mi * 16 + ((lane >> 4) << 2) + reg;
      int m = mbase + m_loc;
      if (m >= count) continue;
      #pragma unroll
      for (int ni = 0; ni < 4; ni++) {
        int n = nbase + nh * 64 + ni * 16 + (lane & 15);
        float v = acc[mi][ni][reg] + bias[n];
        if (FC1) {
          hbuf[(size_t)m * DIM + n] = __float2bfloat16(fast_tanh(v));
        } else {
          unsigned e = wle[m_loc];
          int bidx = e & 511, d = (e >> 9) & 63;
          tfeats[(((size_t)(bidx << 6) + d) << 10) + n] = __float2bfloat16(fast_tanh(v));
          if (e >> 21) rootfeat[(size_t)bidx * DIM + n] = v;
        }
      }
    }
  }
}

// ---------------------------------------------------------------------------
// K7b: deep-level fallback (> LMAX) + fused final scores. One block per bag.
// ---------------------------------------------------------------------------
#define XP(i) ((i) + ((i) >> 3))
__global__ __launch_bounds__(1024) void k_deep(__hip_bfloat16* __restrict__ tfeats,
                                               const __hip_bfloat16* __restrict__ w1b,
                                               const float* __restrict__ b1,
                                               const __hip_bfloat16* __restrict__ w2b,
                                               const float* __restrict__ b2,
                                               const unsigned* __restrict__ lvlbuf,
                                               float* __restrict__ rootfeat,
                                               const float* __restrict__ rel,
                                               float* __restrict__ out) {
  int b = blockIdx.x;
  __shared__ float xs[XP(2048) + 1];
  __shared__ float hs[XP(1024) + 1];
  __shared__ unsigned steps[NSTEP];
  int t = threadIdx.x, wv = t >> 6, lane = t & 63;
  if (t < NSTEP) steps[t] = lvlbuf[b * NSTEP + t];
  __syncthreads();

  for (int s = 0; s < NSTEP; s++) {
    unsigned e = steps[s];
    int lvl = (int)((e >> 12) & 63);
    if (lvl <= LMAX) continue;
    int i1 = (int)(e & 63), i2 = (int)((e >> 6) & 63);
    const __hip_bfloat16* r1 = tfeats + ((((size_t)b << 6) + i1) << 10);
    const __hip_bfloat16* r2 = tfeats + ((((size_t)b << 6) + i2) << 10);
    xs[XP(t)] = __bfloat162float(r1[t]);
    xs[XP(1024 + t)] = __bfloat162float(r2[t]);
    __syncthreads();
    for (int r = 0; r < 64; r++) {
      int n = r * 16 + wv;
      const short8* wr = (const short8*)(w1b + (size_t)n * 2048);
      float acc = 0.f;
      for (int c = lane; c < 256; c += 64) {
        short8 w8 = wr[c];
        #pragma unroll
        for (int j = 0; j < 8; j++) {
          float wf = __uint_as_float(((unsigned)(unsigned short)w8[j]) << 16);
          acc += xs[XP(c * 8 + j)] * wf;
        }
      }
      for (int off = 32; off; off >>= 1) acc += __shfl_xor(acc, off);
      if (lane == 0) hs[XP(n)] = fast_tanh(acc + b1[n]);
    }
    __syncthreads();
    for (int r = 0; r < 64; r++) {
      int n = r * 16 + wv;
      const short8* wr = (const short8*)(w2b + (size_t)n * 1024);
      float acc = 0.f;
      for (int c = lane; c < 128; c += 64) {
        short8 w8 = wr[c];
        #pragma unroll
        for (int j = 0; j < 8; j++) {
          float wf = __uint_as_float(((unsigned)(unsigned short)w8[j]) << 16);
          acc += hs[XP(c * 8 + j)] * wf;
        }
      }
      for (int off = 32; off; off >>= 1) acc += __shfl_xor(acc, off);
      if (lane == 0) {
        float f = acc + b2[n];
        tfeats[((((size_t)b << 6) + i1) << 10) + n] = __float2bfloat16(fast_tanh(f));
        if (s == NSTEP - 1) rootfeat[(size_t)b * DIM + n] = f;
      }
    }
    __syncthreads();
  }

  // ---- fused scores: sigmoid(rootfeat[b] @ rel^T)
  __shared__ float fr[DIM];
  fr[t] = rootfeat[(size_t)b * DIM + t];
  __syncthreads();
  for (int c = wv; c < NCLS; c += 16) {
    const float* w = rel + (size_t)c * DIM;
    float acc = 0.f;
    for (int j = lane; j < DIM; j += 64) acc += fr[j] * w[j];
    for (int off = 32; off; off >>= 1) acc += __shfl_xor(acc, off);
    if (lane == 0) out[b * NCLS + c] = 1.0f / (1.0f + expf(-acc));
  }
}

// ---------------------------------------------------------------------------
extern "C" void kernel_launch(void* const* d_in, const int* in_sizes, int n_in,
                              void* d_out, int out_size, void* d_ws, size_t ws_size,
                              hipStream_t stream) {
  const float* rep = (const float*)d_in[0];
  const float* w1  = (const float*)d_in[1];
  const float* b1  = (const float*)d_in[2];
  const float* w2  = (const float*)d_in[3];
  const float* b2  = (const float*)d_in[4];
  const float* rel = (const float*)d_in[5];
  float* out = (float*)d_out;

  char* ws = (char*)d_ws;
  __hip_bfloat16* tfeats = (__hip_bfloat16*)ws; ws += (size_t)NBAG * NPB * DIM * 2;
  __hip_bfloat16* hbuf   = (__hip_bfloat16*)ws; ws += (size_t)MAXROWS * DIM * 2;
  __hip_bfloat16* w1b    = (__hip_bfloat16*)ws; ws += (size_t)DIM * 2 * DIM * 2;
  __hip_bfloat16* w2b    = (__hip_bfloat16*)ws; ws += (size_t)DIM * DIM * 2;
  float* rootfeat        = (float*)ws;          ws += (size_t)NBAG * DIM * 4;
  float* nw              = (float*)ws;          ws += (size_t)NBAG * NPB * 4;
  float* inv_g           = (float*)ws;          ws += (size_t)NBAG * NPB * 4;
  unsigned* lvlbuf       = (unsigned*)ws;       ws += (size_t)NBAG * NSTEP * 4;
  unsigned* cnt          = (unsigned*)ws;       ws += (size_t)NBAG * 64 * 4;
  unsigned* bagoff       = (unsigned*)ws;       ws += (size_t)64 * 512 * 4;
  unsigned* levtot       = (unsigned*)ws;       ws += 64 * 4;
  unsigned* off          = (unsigned*)ws;       ws += 128 * 4;
  unsigned* wl           = (unsigned*)ws;       ws += (size_t)NBAG * NSTEP * 4;

  k_prep_a<<<NBAG * 4, 256, 0, stream>>>(rep, inv_g, tfeats, w1, w1b, w2, w2b);
  k_prep_b<<<NBAG, 1024, 0, stream>>>(rep, inv_g, nw);
  k_merge_levels<<<NBAG / 4, 256, 0, stream>>>(nw, lvlbuf, cnt);
  k_bagscan<<<63, 512, 0, stream>>>(cnt, bagoff, levtot);
  k_scatter<<<126, 256, 0, stream>>>(lvlbuf, levtot, bagoff, wl, off);

  for (int l = 1; l <= LMAX; l++) {
    int cap = 64 / (l + 1); if (cap > 32) cap = 32;
    int capM = 2 * cap;                       // 256-row M-tiles capacity
    k_fc<2 * DIM, true><<<dim3(8 * capM), 512, 0, stream>>>(
        tfeats, w1b, b1, wl, off, hbuf, nullptr, nullptr, l);
    k_fc<DIM, false><<<dim3(8 * capM), 512, 0, stream>>>(
        hbuf, w2b, b2, wl, off, nullptr, tfeats, rootfeat, l);
  }
  k_deep<<<NBAG, 1024, 0, stream>>>(tfeats, w1b, b1, w2b, b2, lvlbuf, rootfeat,
                                    rel, out);
}